// Round 1
// baseline (302.867 us; speedup 1.0000x reference)
//
#include <hip/hip_runtime.h>
#include <hip/hip_bf16.h>
#include <math.h>

typedef __bf16 bf16_t;
typedef __bf16 bf8 __attribute__((ext_vector_type(8)));
typedef __bf16 bf16x2 __attribute__((ext_vector_type(2)));
typedef float f32x4 __attribute__((ext_vector_type(4)));

#define B_ROWS 4096
#define NTOT   8192
#define DIN    1024
#define DENC   512
#define DH     256
#define DP     128
#define INV_T        14.285714285714286f   // 1/0.07
#define SCALE_LOG2   20.609929155556620f   // log2(e)/0.07

__device__ __forceinline__ f32x4 mfma_16x16x32(bf8 a, bf8 b, f32x4 c) {
  return __builtin_amdgcn_mfma_f32_16x16x32_bf16(a, b, c, 0, 0, 0);
}

// ---------------------------------------------------------------------------
// prep: cast x (both modalities) to bf16; transpose+cast all 6 weight
// matrices to [N][K] bf16 (Bt form) so every GEMM operand load is a
// contiguous row read.
// ---------------------------------------------------------------------------
__global__ __launch_bounds__(256) void prep_kernel(
    const float* __restrict__ x_img, const float* __restrict__ x_txt,
    const float* __restrict__ We_img, const float* __restrict__ We_txt,
    const float* __restrict__ W1_img, const float* __restrict__ W1_txt,
    const float* __restrict__ W2_img, const float* __restrict__ W2_txt,
    bf16_t* __restrict__ xbf_img, bf16_t* __restrict__ xbf_txt,
    bf16_t* __restrict__ Wet_img, bf16_t* __restrict__ Wet_txt,
    bf16_t* __restrict__ W1t_img, bf16_t* __restrict__ W1t_txt,
    bf16_t* __restrict__ W2t_img, bf16_t* __restrict__ W2t_txt) {
  int idx = blockIdx.x * 256 + threadIdx.x;
  const int XN  = B_ROWS * DIN;   // 4194304
  const int WEN = DIN * DENC;     // 524288
  const int W1N = DENC * DH;      // 131072
  const int W2N = DH * DP;        // 32768
  if (idx < XN) { xbf_img[idx] = (bf16_t)x_img[idx]; return; }
  idx -= XN;
  if (idx < XN) { xbf_txt[idx] = (bf16_t)x_txt[idx]; return; }
  idx -= XN;
  if (idx < WEN) { int n = idx >> 10, k = idx & 1023; Wet_img[idx] = (bf16_t)We_img[k * DENC + n]; return; }
  idx -= WEN;
  if (idx < WEN) { int n = idx >> 10, k = idx & 1023; Wet_txt[idx] = (bf16_t)We_txt[k * DENC + n]; return; }
  idx -= WEN;
  if (idx < W1N) { int n = idx >> 9, k = idx & 511; W1t_img[idx] = (bf16_t)W1_img[k * DH + n]; return; }
  idx -= W1N;
  if (idx < W1N) { int n = idx >> 9, k = idx & 511; W1t_txt[idx] = (bf16_t)W1_txt[k * DH + n]; return; }
  idx -= W1N;
  if (idx < W2N) { int n = idx >> 8, k = idx & 255; W2t_img[idx] = (bf16_t)W2_img[k * DP + n]; return; }
  idx -= W2N;
  if (idx < W2N) { int n = idx >> 8, k = idx & 255; W2t_txt[idx] = (bf16_t)W2_txt[k * DP + n]; return; }
}

// ---------------------------------------------------------------------------
// gemm_bt: C[M][N] = A[M][K] * Bt[N][K]^T + bias, optional ReLU.
// 64x64 tile, BK=32, 256 threads (4 waves, each: 16 rows x 64 cols).
// LDS rows padded to 40 bf16 (80B) -> ds_read_b128 conflicts <=2-way (free).
// MFMA 16x16x32 bf16; verified layouts: A-frag m=lane&15,k=quad*8+j;
// C/D col=lane&15,row=quad*4+reg.
// ---------------------------------------------------------------------------
template<bool RELU, bool F32OUT>
__global__ __launch_bounds__(256) void gemm_bt(
    const bf16_t* __restrict__ A, const bf16_t* __restrict__ Bt,
    const float* __restrict__ bias, void* __restrict__ outp,
    int M, int N, int K) {
  const int nb   = blockIdx.x * 64;
  const int mb   = blockIdx.y * 64;
  const int tid  = threadIdx.x;
  const int wave = tid >> 6;
  const int lane = tid & 63;
  const int l15  = lane & 15;
  const int quad = lane >> 4;

  __shared__ __align__(16) bf16_t As[64][40];
  __shared__ __align__(16) bf16_t Bs[64][40];

  f32x4 acc[4];
  #pragma unroll
  for (int i = 0; i < 4; ++i) acc[i] = (f32x4){0.f, 0.f, 0.f, 0.f};

  const int srow   = tid >> 2;         // 0..63
  const int schunk = (tid & 3) << 3;   // 0,8,16,24 (bf16 elems)
  const bf16_t* Ap = A  + (size_t)(mb + srow) * K + schunk;
  const bf16_t* Bp = Bt + (size_t)(nb + srow) * K + schunk;

  for (int k0 = 0; k0 < K; k0 += 32) {
    uint4 av = *(const uint4*)(Ap + k0);
    uint4 bv = *(const uint4*)(Bp + k0);
    __syncthreads();
    *(uint4*)&As[srow][schunk] = av;
    *(uint4*)&Bs[srow][schunk] = bv;
    __syncthreads();
    bf8 af = *(const bf8*)&As[wave * 16 + l15][quad * 8];
    #pragma unroll
    for (int nt = 0; nt < 4; ++nt) {
      bf8 bfv = *(const bf8*)&Bs[nt * 16 + l15][quad * 8];
      acc[nt] = mfma_16x16x32(af, bfv, acc[nt]);
    }
  }

  const int orow = mb + wave * 16 + quad * 4;
  #pragma unroll
  for (int nt = 0; nt < 4; ++nt) {
    const int ocol = nb + nt * 16 + l15;
    const float bval = bias[ocol];
    #pragma unroll
    for (int r = 0; r < 4; ++r) {
      float v = acc[nt][r] + bval;
      if (RELU) v = fmaxf(v, 0.f);
      if (F32OUT) ((float*)outp)[(size_t)(orow + r) * N + ocol] = v;
      else        ((bf16_t*)outp)[(size_t)(orow + r) * N + ocol] = (bf16_t)v;
    }
  }
}

// ---------------------------------------------------------------------------
// normalize: one wave per row; L2-normalize z rows (clamp 1e-12), emit bf16.
// ---------------------------------------------------------------------------
__global__ __launch_bounds__(256) void normalize_kernel(
    const float* __restrict__ z, bf16_t* __restrict__ reps) {
  const int row  = blockIdx.x * 4 + (threadIdx.x >> 6);
  const int lane = threadIdx.x & 63;
  const float2 v = *(const float2*)(z + (size_t)row * DP + lane * 2);
  float ss = v.x * v.x + v.y * v.y;
  #pragma unroll
  for (int m = 1; m < 64; m <<= 1) ss += __shfl_xor(ss, m);
  const float inv = 1.0f / fmaxf(sqrtf(ss), 1e-12f);
  bf16x2 st;
  st.x = (bf16_t)(v.x * inv);
  st.y = (bf16_t)(v.y * inv);
  *(bf16x2*)(reps + (size_t)row * DP + lane * 2) = st;
}

// ---------------------------------------------------------------------------
// sim_rowsum: fused reps·repsᵀ + weighted exp row-sums. Never materializes
// the 8192x8192 sim matrix. Denominator per row i:
//   S_i = sum_j w_ij * exp(sim_ij/t),  w: diag=0, positive col (i^4096)=2,
// which equals exp(pos/t) + sum_{j != i} exp(sim_ij/t) (positive counted
// twice per reference's logits construction). sim<=1 -> exp sums < 1.4e10,
// fp32-safe with no online max. Also captures pos_i (unique writer).
// Grid: (4 column slices, 128 row blocks of 64). 4 waves/WG, wave = 16 rows.
// ---------------------------------------------------------------------------
__global__ __launch_bounds__(256) void sim_rowsum_kernel(
    const bf16_t* __restrict__ reps, float* __restrict__ S,
    float* __restrict__ Pos) {
  const int rowbase = blockIdx.y * 64;
  const int col0    = blockIdx.x * 2048;
  const int tid  = threadIdx.x;
  const int wave = tid >> 6;
  const int lane = tid & 63;
  const int l15  = lane & 15;
  const int quad = lane >> 4;

  // A-fragments for this wave's 16 rows, all of K=128, held in registers.
  const int arow = rowbase + wave * 16 + l15;
  bf8 afrag[4];
  #pragma unroll
  for (int kt = 0; kt < 4; ++kt)
    afrag[kt] = *(const bf8*)(reps + (size_t)arow * DP + kt * 32 + quad * 8);

  float rsum[4] = {0.f, 0.f, 0.f, 0.f};
  const int irow0 = rowbase + wave * 16 + quad * 4;  // C-layout rows

  for (int jt = col0; jt < col0 + 2048; jt += 16) {
    const int jcol = jt + l15;   // B-frag: n = lane&15
    f32x4 acc = (f32x4){0.f, 0.f, 0.f, 0.f};
    #pragma unroll
    for (int kt = 0; kt < 4; ++kt) {
      bf8 bfv = *(const bf8*)(reps + (size_t)jcol * DP + kt * 32 + quad * 8);
      acc = mfma_16x16x32(afrag[kt], bfv, acc);
    }
    #pragma unroll
    for (int r = 0; r < 4; ++r) {
      const int irow = irow0 + r;
      const float s = acc[r];
      const float e = exp2f(s * SCALE_LOG2);
      float w = 1.f;
      if (jcol == irow) w = 0.f;
      if (jcol == (irow ^ 4096)) { w = 2.f; Pos[irow] = s; }
      rsum[r] += w * e;
    }
  }

  // Reduce across the 16 lanes sharing this quad (xor bits 0..3 stay in group)
  #pragma unroll
  for (int r = 0; r < 4; ++r) {
    float v = rsum[r];
    v += __shfl_xor(v, 1);
    v += __shfl_xor(v, 2);
    v += __shfl_xor(v, 4);
    v += __shfl_xor(v, 8);
    if (l15 == 0) atomicAdd(&S[irow0 + r], v);
  }
}

// ---------------------------------------------------------------------------
// finalize: loss = mean_i( log(S_i) - pos_i/t )
// ---------------------------------------------------------------------------
__global__ __launch_bounds__(1024) void finalize_kernel(
    const float* __restrict__ S, const float* __restrict__ Pos,
    float* __restrict__ out) {
  const int tid = threadIdx.x;
  float acc = 0.f;
  for (int i = tid; i < NTOT; i += 1024)
    acc += logf(S[i]) - Pos[i] * INV_T;
  #pragma unroll
  for (int m = 1; m < 64; m <<= 1) acc += __shfl_xor(acc, m);
  __shared__ float wsum[16];
  if ((tid & 63) == 0) wsum[tid >> 6] = acc;
  __syncthreads();
  if (tid < 16) {
    float v = wsum[tid];
    #pragma unroll
    for (int m = 1; m < 16; m <<= 1) v += __shfl_xor(v, m);
    if (tid == 0) out[0] = v * (1.0f / NTOT);
  }
}

// ---------------------------------------------------------------------------
extern "C" void kernel_launch(void* const* d_in, const int* in_sizes, int n_in,
                              void* d_out, int out_size, void* d_ws, size_t ws_size,
                              hipStream_t stream) {
  const float* x_img  = (const float*)d_in[0];
  const float* x_txt  = (const float*)d_in[1];
  const float* We_img = (const float*)d_in[2];
  const float* be_img = (const float*)d_in[3];
  const float* We_txt = (const float*)d_in[4];
  const float* be_txt = (const float*)d_in[5];
  const float* W1_img = (const float*)d_in[6];
  const float* b1_img = (const float*)d_in[7];
  const float* W2_img = (const float*)d_in[8];
  const float* b2_img = (const float*)d_in[9];
  const float* W1_txt = (const float*)d_in[10];
  const float* b1_txt = (const float*)d_in[11];
  const float* W2_txt = (const float*)d_in[12];
  const float* b2_txt = (const float*)d_in[13];

  char* p = (char*)d_ws;
  bf16_t* xbf_img = (bf16_t*)p; p += (size_t)B_ROWS * DIN * 2;
  bf16_t* xbf_txt = (bf16_t*)p; p += (size_t)B_ROWS * DIN * 2;
  bf16_t* Wet_img = (bf16_t*)p; p += (size_t)DENC * DIN * 2;
  bf16_t* Wet_txt = (bf16_t*)p; p += (size_t)DENC * DIN * 2;
  bf16_t* W1t_img = (bf16_t*)p; p += (size_t)DH * DENC * 2;
  bf16_t* W1t_txt = (bf16_t*)p; p += (size_t)DH * DENC * 2;
  bf16_t* W2t_img = (bf16_t*)p; p += (size_t)DP * DH * 2;
  bf16_t* W2t_txt = (bf16_t*)p; p += (size_t)DP * DH * 2;
  bf16_t* h_img   = (bf16_t*)p; p += (size_t)B_ROWS * DENC * 2;
  bf16_t* h_txt   = (bf16_t*)p; p += (size_t)B_ROWS * DENC * 2;
  bf16_t* g_img   = (bf16_t*)p; p += (size_t)B_ROWS * DH * 2;
  bf16_t* g_txt   = (bf16_t*)p; p += (size_t)B_ROWS * DH * 2;
  float*  z       = (float*) p; p += (size_t)NTOT * DP * 4;   // img rows 0..4095, txt 4096..8191
  bf16_t* reps    = (bf16_t*)p; p += (size_t)NTOT * DP * 2;
  float*  S       = (float*) p; p += (size_t)NTOT * 4;
  float*  Pos     = (float*) p; p += (size_t)NTOT * 4;

  hipMemsetAsync(S, 0, (size_t)NTOT * 4, stream);

  prep_kernel<<<38144, 256, 0, stream>>>(
      x_img, x_txt, We_img, We_txt, W1_img, W1_txt, W2_img, W2_txt,
      xbf_img, xbf_txt, Wet_img, Wet_txt, W1t_img, W1t_txt, W2t_img, W2t_txt);

  // encoder: h = x @ We + be   [4096x512], K=1024
  gemm_bt<false,false><<<dim3(DENC/64, B_ROWS/64), 256, 0, stream>>>(
      xbf_img, Wet_img, be_img, h_img, B_ROWS, DENC, DIN);
  gemm_bt<false,false><<<dim3(DENC/64, B_ROWS/64), 256, 0, stream>>>(
      xbf_txt, Wet_txt, be_txt, h_txt, B_ROWS, DENC, DIN);
  // head 1: g = relu(h @ W1 + b1)   [4096x256], K=512
  gemm_bt<true,false><<<dim3(DH/64, B_ROWS/64), 256, 0, stream>>>(
      h_img, W1t_img, b1_img, g_img, B_ROWS, DH, DENC);
  gemm_bt<true,false><<<dim3(DH/64, B_ROWS/64), 256, 0, stream>>>(
      h_txt, W1t_txt, b1_txt, g_txt, B_ROWS, DH, DENC);
  // head 2: z = g @ W2 + b2   [4096x128] f32, K=256
  gemm_bt<false,true><<<dim3(DP/64, B_ROWS/64), 256, 0, stream>>>(
      g_img, W2t_img, b2_img, z, B_ROWS, DP, DH);
  gemm_bt<false,true><<<dim3(DP/64, B_ROWS/64), 256, 0, stream>>>(
      g_txt, W2t_txt, b2_txt, z + (size_t)B_ROWS * DP, B_ROWS, DP, DH);

  normalize_kernel<<<NTOT/4, 256, 0, stream>>>(z, reps);
  sim_rowsum_kernel<<<dim3(4, NTOT/64), 256, 0, stream>>>(reps, S, Pos);
  finalize_kernel<<<1, 1024, 0, stream>>>(S, Pos, (float*)d_out);
}

// Round 2
// 226.763 us; speedup vs baseline: 1.3356x; 1.3356x over previous
//
#include <hip/hip_runtime.h>
#include <hip/hip_bf16.h>
#include <math.h>

typedef __bf16 bf16_t;
typedef __bf16 bf8 __attribute__((ext_vector_type(8)));
typedef __bf16 bf4 __attribute__((ext_vector_type(4)));
typedef __bf16 bf16x2 __attribute__((ext_vector_type(2)));
typedef float f32x4 __attribute__((ext_vector_type(4)));

#define B_ROWS 4096
#define NTOT   8192
#define DIN    1024
#define DENC   512
#define DH     256
#define DP     128
#define INV_T        14.285714285714286f   // 1/0.07
#define SCALE_LOG2   20.609929155556620f   // log2(e)/0.07

__device__ __forceinline__ f32x4 mfma_16x16x32(bf8 a, bf8 b, f32x4 c) {
  return __builtin_amdgcn_mfma_f32_16x16x32_bf16(a, b, c, 0, 0, 0);
}

// ---------------------------------------------------------------------------
// cast_kernel: x (both modalities) f32 -> bf16, float4 loads / 8B stores.
// ---------------------------------------------------------------------------
__global__ __launch_bounds__(256) void cast_kernel(
    const float* __restrict__ xi, const float* __restrict__ xt,
    bf16_t* __restrict__ oi, bf16_t* __restrict__ ot) {
  int idx = blockIdx.x * 256 + threadIdx.x;      // 0 .. 2*1048576-1
  const int HALF = (B_ROWS * DIN) / 4;           // 1048576 float4 chunks
  const float* s; bf16_t* d; int off;
  if (idx < HALF) { s = xi; d = oi; off = idx; }
  else            { s = xt; d = ot; off = idx - HALF; }
  float4 v = ((const float4*)s)[off];
  bf4 w = { (bf16_t)v.x, (bf16_t)v.y, (bf16_t)v.z, (bf16_t)v.w };
  ((bf4*)d)[off] = w;
}

// ---------------------------------------------------------------------------
// transpose_kernel: all six weight matrices [K][N] f32 -> [N][K] bf16 via
// LDS 64x64 tiles; coalesced reads AND writes. 336 blocks total.
// ---------------------------------------------------------------------------
__global__ __launch_bounds__(256) void transpose_kernel(
    const float* __restrict__ We_i, const float* __restrict__ We_t,
    const float* __restrict__ W1_i, const float* __restrict__ W1_t,
    const float* __restrict__ W2_i, const float* __restrict__ W2_t,
    bf16_t* __restrict__ Wet_i, bf16_t* __restrict__ Wet_t,
    bf16_t* __restrict__ W1t_i, bf16_t* __restrict__ W1t_t,
    bf16_t* __restrict__ W2t_i, bf16_t* __restrict__ W2t_t) {
  const int b = blockIdx.x;
  const float* src; bf16_t* dst; int K, N, tile;
  if (b < 128)      { src = We_i; dst = Wet_i; K = 1024; N = 512; tile = b; }
  else if (b < 256) { src = We_t; dst = Wet_t; K = 1024; N = 512; tile = b - 128; }
  else if (b < 288) { src = W1_i; dst = W1t_i; K = 512;  N = 256; tile = b - 256; }
  else if (b < 320) { src = W1_t; dst = W1t_t; K = 512;  N = 256; tile = b - 288; }
  else if (b < 328) { src = W2_i; dst = W2t_i; K = 256;  N = 128; tile = b - 320; }
  else              { src = W2_t; dst = W2t_t; K = 256;  N = 128; tile = b - 328; }
  const int tilesN = N >> 6;
  const int k0 = (tile / tilesN) * 64;
  const int n0 = (tile % tilesN) * 64;
  const int tid = threadIdx.x;

  __shared__ float ld[64][65];
  #pragma unroll
  for (int i = 0; i < 4; ++i) {
    int cid = tid + i * 256;          // 0..1023
    int r = cid >> 4;                 // k-row 0..63
    int c = (cid & 15) * 4;           // n-col chunk
    float4 v = *(const float4*)(src + (size_t)(k0 + r) * N + n0 + c);
    ld[r][c + 0] = v.x; ld[r][c + 1] = v.y; ld[r][c + 2] = v.z; ld[r][c + 3] = v.w;
  }
  __syncthreads();
  #pragma unroll
  for (int i = 0; i < 2; ++i) {
    int cid = tid + i * 256;          // 0..511
    int rn = cid >> 3;                // n-row 0..63
    int c8 = (cid & 7) * 8;           // k chunk
    bf8 w;
    #pragma unroll
    for (int j = 0; j < 8; ++j) w[j] = (bf16_t)ld[c8 + j][rn];
    *(bf8*)(dst + (size_t)(n0 + rn) * K + k0 + c8) = w;
  }
}

// ---------------------------------------------------------------------------
// gemm64: paired (img/txt via blockIdx.z) C = A[M][K] * Bt[N][K]^T + bias,
// optional ReLU, bf16 out. 64x64 tile, BK=32, 4 waves.
// ---------------------------------------------------------------------------
template<bool RELU>
__global__ __launch_bounds__(256) void gemm64(
    const bf16_t* __restrict__ A0, const bf16_t* __restrict__ A1,
    const bf16_t* __restrict__ B0, const bf16_t* __restrict__ B1,
    const float* __restrict__ bias0, const float* __restrict__ bias1,
    bf16_t* __restrict__ out0, bf16_t* __restrict__ out1,
    int N, int K) {
  const bf16_t* A   = blockIdx.z ? A1 : A0;
  const bf16_t* Bt  = blockIdx.z ? B1 : B0;
  const float* bias = blockIdx.z ? bias1 : bias0;
  bf16_t* outp      = blockIdx.z ? out1 : out0;

  const int nb   = blockIdx.x * 64;
  const int mb   = blockIdx.y * 64;
  const int tid  = threadIdx.x;
  const int wave = tid >> 6;
  const int lane = tid & 63;
  const int l15  = lane & 15;
  const int quad = lane >> 4;

  __shared__ __align__(16) bf16_t As[64][40];
  __shared__ __align__(16) bf16_t Bs[64][40];

  f32x4 acc[4];
  #pragma unroll
  for (int i = 0; i < 4; ++i) acc[i] = (f32x4){0.f, 0.f, 0.f, 0.f};

  const int srow   = tid >> 2;
  const int schunk = (tid & 3) << 3;
  const bf16_t* Ap = A  + (size_t)(mb + srow) * K + schunk;
  const bf16_t* Bp = Bt + (size_t)(nb + srow) * K + schunk;

  for (int k0 = 0; k0 < K; k0 += 32) {
    uint4 av = *(const uint4*)(Ap + k0);
    uint4 bv = *(const uint4*)(Bp + k0);
    __syncthreads();
    *(uint4*)&As[srow][schunk] = av;
    *(uint4*)&Bs[srow][schunk] = bv;
    __syncthreads();
    bf8 af = *(const bf8*)&As[wave * 16 + l15][quad * 8];
    #pragma unroll
    for (int nt = 0; nt < 4; ++nt) {
      bf8 bfv = *(const bf8*)&Bs[nt * 16 + l15][quad * 8];
      acc[nt] = mfma_16x16x32(af, bfv, acc[nt]);
    }
  }

  const int orow = mb + wave * 16 + quad * 4;
  #pragma unroll
  for (int nt = 0; nt < 4; ++nt) {
    const int ocol = nb + nt * 16 + l15;
    const float bval = bias[ocol];
    #pragma unroll
    for (int r = 0; r < 4; ++r) {
      float v = acc[nt][r] + bval;
      if (RELU) v = fmaxf(v, 0.f);
      outp[(size_t)(orow + r) * N + ocol] = (bf16_t)v;
    }
  }
}

// ---------------------------------------------------------------------------
// head2_norm: paired z = g @ W2t^T + b2 (K=256, N=128) with FUSED L2
// normalization; emits bf16 reps directly (z never hits memory).
// Block: 64 rows, wave = 16 rows x all 128 cols (8 n-tiles).
// ---------------------------------------------------------------------------
__global__ __launch_bounds__(256) void head2_norm(
    const bf16_t* __restrict__ A0, const bf16_t* __restrict__ A1,
    const bf16_t* __restrict__ B0, const bf16_t* __restrict__ B1,
    const float* __restrict__ bias0, const float* __restrict__ bias1,
    bf16_t* __restrict__ reps) {
  const bf16_t* A   = blockIdx.z ? A1 : A0;
  const bf16_t* Bt  = blockIdx.z ? B1 : B0;
  const float* bias = blockIdx.z ? bias1 : bias0;

  const int mb   = blockIdx.x * 64;
  const int tid  = threadIdx.x;
  const int wave = tid >> 6;
  const int lane = tid & 63;
  const int l15  = lane & 15;
  const int quad = lane >> 4;

  __shared__ __align__(16) bf16_t As[64][40];
  __shared__ __align__(16) bf16_t Bs[128][40];

  f32x4 acc[8];
  #pragma unroll
  for (int i = 0; i < 8; ++i) acc[i] = (f32x4){0.f, 0.f, 0.f, 0.f};

  const int arow   = tid >> 2;
  const int achunk = (tid & 3) << 3;
  const bf16_t* Ap = A + (size_t)(mb + arow) * DH + achunk;

  for (int k0 = 0; k0 < DH; k0 += 32) {
    uint4 av = *(const uint4*)(Ap + k0);
    uint4 bv[2];
    #pragma unroll
    for (int i = 0; i < 2; ++i) {
      int cid = tid + i * 256;
      int br = cid >> 2, bc = (cid & 3) << 3;
      bv[i] = *(const uint4*)(Bt + (size_t)br * DH + k0 + bc);
    }
    __syncthreads();
    *(uint4*)&As[arow][achunk] = av;
    #pragma unroll
    for (int i = 0; i < 2; ++i) {
      int cid = tid + i * 256;
      int br = cid >> 2, bc = (cid & 3) << 3;
      *(uint4*)&Bs[br][bc] = bv[i];
    }
    __syncthreads();
    bf8 af = *(const bf8*)&As[wave * 16 + l15][quad * 8];
    #pragma unroll
    for (int nt = 0; nt < 8; ++nt) {
      bf8 bfv = *(const bf8*)&Bs[nt * 16 + l15][quad * 8];
      acc[nt] = mfma_16x16x32(af, bfv, acc[nt]);
    }
  }

  // bias
  #pragma unroll
  for (int nt = 0; nt < 8; ++nt) {
    const float bval = bias[nt * 16 + l15];
    #pragma unroll
    for (int r = 0; r < 4; ++r) acc[nt][r] += bval;
  }
  // per-row L2 norm (rows quad*4+r; cols spread over l15 x 8 n-tiles)
  const size_t rowbase = (size_t)(blockIdx.z ? B_ROWS : 0) + mb + wave * 16 + quad * 4;
  #pragma unroll
  for (int r = 0; r < 4; ++r) {
    float ss = 0.f;
    #pragma unroll
    for (int nt = 0; nt < 8; ++nt) ss += acc[nt][r] * acc[nt][r];
    ss += __shfl_xor(ss, 1);
    ss += __shfl_xor(ss, 2);
    ss += __shfl_xor(ss, 4);
    ss += __shfl_xor(ss, 8);
    const float inv = 1.0f / fmaxf(sqrtf(ss), 1e-12f);
    #pragma unroll
    for (int nt = 0; nt < 8; ++nt)
      reps[(rowbase + r) * DP + nt * 16 + l15] = (bf16_t)(acc[nt][r] * inv);
  }
}

// ---------------------------------------------------------------------------
// sim_rowsum: fused reps·repsᵀ + UNWEIGHTED exp row-sums (raw). Diagonal and
// positive-pair corrections are applied later in rowloss_kernel, so the hot
// loop is compare-free: rsum += exp2(sim * log2e/t).
// Grid (16 col-slices, 64 row-blocks of 128). Wave = 2 row-sets of 16 (2
// independent MFMA chains per B-frag load -> 2x ILP, half the B traffic).
// sim<=1 -> sums < 1.4e10, fp32-safe without online max.
// ---------------------------------------------------------------------------
__global__ __launch_bounds__(256) void sim_rowsum_kernel(
    const bf16_t* __restrict__ reps, float* __restrict__ S) {
  const int rowbase = blockIdx.y * 128;
  const int col0    = blockIdx.x * 512;
  const int tid  = threadIdx.x;
  const int wave = tid >> 6;
  const int lane = tid & 63;
  const int l15  = lane & 15;
  const int quad = lane >> 4;

  const int r0 = rowbase + wave * 32;
  bf8 af0[4], af1[4];
  #pragma unroll
  for (int kt = 0; kt < 4; ++kt) {
    af0[kt] = *(const bf8*)(reps + (size_t)(r0 + l15)      * DP + kt * 32 + quad * 8);
    af1[kt] = *(const bf8*)(reps + (size_t)(r0 + 16 + l15) * DP + kt * 32 + quad * 8);
  }

  float rs0[4] = {0.f, 0.f, 0.f, 0.f};
  float rs1[4] = {0.f, 0.f, 0.f, 0.f};

  for (int jt = col0; jt < col0 + 512; jt += 16) {
    const bf16_t* bp = reps + (size_t)(jt + l15) * DP + quad * 8;
    bf8 b0 = *(const bf8*)(bp);
    bf8 b1 = *(const bf8*)(bp + 32);
    bf8 b2 = *(const bf8*)(bp + 64);
    bf8 b3 = *(const bf8*)(bp + 96);
    f32x4 acc0 = (f32x4){0.f, 0.f, 0.f, 0.f};
    f32x4 acc1 = (f32x4){0.f, 0.f, 0.f, 0.f};
    acc0 = mfma_16x16x32(af0[0], b0, acc0); acc1 = mfma_16x16x32(af1[0], b0, acc1);
    acc0 = mfma_16x16x32(af0[1], b1, acc0); acc1 = mfma_16x16x32(af1[1], b1, acc1);
    acc0 = mfma_16x16x32(af0[2], b2, acc0); acc1 = mfma_16x16x32(af1[2], b2, acc1);
    acc0 = mfma_16x16x32(af0[3], b3, acc0); acc1 = mfma_16x16x32(af1[3], b3, acc1);
    #pragma unroll
    for (int r = 0; r < 4; ++r) {
      rs0[r] += __builtin_amdgcn_exp2f(acc0[r] * SCALE_LOG2);
      rs1[r] += __builtin_amdgcn_exp2f(acc1[r] * SCALE_LOG2);
    }
  }

  const int i0 = r0 + quad * 4;
  #pragma unroll
  for (int r = 0; r < 4; ++r) {
    float v = rs0[r];
    v += __shfl_xor(v, 1); v += __shfl_xor(v, 2);
    v += __shfl_xor(v, 4); v += __shfl_xor(v, 8);
    if (l15 == 0) atomicAdd(&S[i0 + r], v);
  }
  #pragma unroll
  for (int r = 0; r < 4; ++r) {
    float v = rs1[r];
    v += __shfl_xor(v, 1); v += __shfl_xor(v, 2);
    v += __shfl_xor(v, 4); v += __shfl_xor(v, 8);
    if (l15 == 0) atomicAdd(&S[i0 + 16 + r], v);
  }
}

// ---------------------------------------------------------------------------
// rowloss: per row i recompute d_ii = <r_i,r_i>, pos = <r_i,r_{i^B}> from
// reps (fp32 over bf16), correct the raw sum, emit per-row loss:
//   L_i = log(S_raw - exp(d_ii/t) + exp(pos/t)) - pos/t
// One wave per row.
// ---------------------------------------------------------------------------
__global__ __launch_bounds__(256) void rowloss_kernel(
    const bf16_t* __restrict__ reps, const float* __restrict__ S,
    float* __restrict__ L) {
  const int row  = blockIdx.x * 4 + (threadIdx.x >> 6);
  const int lane = threadIdx.x & 63;
  bf16x2 a = *(const bf16x2*)(reps + (size_t)row * DP + lane * 2);
  bf16x2 b = *(const bf16x2*)(reps + (size_t)(row ^ B_ROWS) * DP + lane * 2);
  float a0 = (float)a.x, a1 = (float)a.y;
  float b0 = (float)b.x, b1 = (float)b.y;
  float dii = a0 * a0 + a1 * a1;
  float pos = a0 * b0 + a1 * b1;
  #pragma unroll
  for (int m = 1; m < 64; m <<= 1) {
    dii += __shfl_xor(dii, m);
    pos += __shfl_xor(pos, m);
  }
  if (lane == 0) {
    float Si = S[row] - __builtin_amdgcn_exp2f(dii * SCALE_LOG2)
                      + __builtin_amdgcn_exp2f(pos * SCALE_LOG2);
    L[row] = logf(Si) - pos * INV_T;
  }
}

// ---------------------------------------------------------------------------
// reduce: mean over 8192 per-row losses -> d_out[0]
// ---------------------------------------------------------------------------
__global__ __launch_bounds__(1024) void reduce_kernel(
    const float* __restrict__ L, float* __restrict__ out) {
  const int tid = threadIdx.x;
  float acc = 0.f;
  for (int i = tid; i < NTOT; i += 1024) acc += L[i];
  #pragma unroll
  for (int m = 1; m < 64; m <<= 1) acc += __shfl_xor(acc, m);
  __shared__ float wsum[16];
  if ((tid & 63) == 0) wsum[tid >> 6] = acc;
  __syncthreads();
  if (tid < 16) {
    float v = wsum[tid];
    #pragma unroll
    for (int m = 1; m < 16; m <<= 1) v += __shfl_xor(v, m);
    if (tid == 0) out[0] = v * (1.0f / NTOT);
  }
}

// ---------------------------------------------------------------------------
extern "C" void kernel_launch(void* const* d_in, const int* in_sizes, int n_in,
                              void* d_out, int out_size, void* d_ws, size_t ws_size,
                              hipStream_t stream) {
  const float* x_img  = (const float*)d_in[0];
  const float* x_txt  = (const float*)d_in[1];
  const float* We_img = (const float*)d_in[2];
  const float* be_img = (const float*)d_in[3];
  const float* We_txt = (const float*)d_in[4];
  const float* be_txt = (const float*)d_in[5];
  const float* W1_img = (const float*)d_in[6];
  const float* b1_img = (const float*)d_in[7];
  const float* W2_img = (const float*)d_in[8];
  const float* b2_img = (const float*)d_in[9];
  const float* W1_txt = (const float*)d_in[10];
  const float* b1_txt = (const float*)d_in[11];
  const float* W2_txt = (const float*)d_in[12];
  const float* b2_txt = (const float*)d_in[13];

  char* p = (char*)d_ws;
  bf16_t* xbf_img = (bf16_t*)p; p += (size_t)B_ROWS * DIN * 2;
  bf16_t* xbf_txt = (bf16_t*)p; p += (size_t)B_ROWS * DIN * 2;
  bf16_t* Wet_img = (bf16_t*)p; p += (size_t)DENC * DIN * 2;
  bf16_t* Wet_txt = (bf16_t*)p; p += (size_t)DENC * DIN * 2;
  bf16_t* W1t_img = (bf16_t*)p; p += (size_t)DH * DENC * 2;
  bf16_t* W1t_txt = (bf16_t*)p; p += (size_t)DH * DENC * 2;
  bf16_t* W2t_img = (bf16_t*)p; p += (size_t)DP * DH * 2;
  bf16_t* W2t_txt = (bf16_t*)p; p += (size_t)DP * DH * 2;
  bf16_t* h_img   = (bf16_t*)p; p += (size_t)B_ROWS * DENC * 2;
  bf16_t* h_txt   = (bf16_t*)p; p += (size_t)B_ROWS * DENC * 2;
  bf16_t* g_img   = (bf16_t*)p; p += (size_t)B_ROWS * DH * 2;
  bf16_t* g_txt   = (bf16_t*)p; p += (size_t)B_ROWS * DH * 2;
  bf16_t* reps    = (bf16_t*)p; p += (size_t)NTOT * DP * 2;
  float*  S       = (float*) p; p += (size_t)NTOT * 4;
  float*  L       = (float*) p; p += (size_t)NTOT * 4;

  hipMemsetAsync(S, 0, (size_t)NTOT * 4, stream);

  cast_kernel<<<(B_ROWS * DIN * 2 / 4) / 256, 256, 0, stream>>>(
      x_img, x_txt, xbf_img, xbf_txt);
  transpose_kernel<<<336, 256, 0, stream>>>(
      We_img, We_txt, W1_img, W1_txt, W2_img, W2_txt,
      Wet_img, Wet_txt, W1t_img, W1t_txt, W2t_img, W2t_txt);

  // encoder: h = x @ We + be   [4096x512], K=1024  (img & txt via z)
  gemm64<false><<<dim3(DENC / 64, B_ROWS / 64, 2), 256, 0, stream>>>(
      xbf_img, xbf_txt, Wet_img, Wet_txt, be_img, be_txt, h_img, h_txt,
      DENC, DIN);
  // head 1: g = relu(h @ W1 + b1)   [4096x256], K=512
  gemm64<true><<<dim3(DH / 64, B_ROWS / 64, 2), 256, 0, stream>>>(
      h_img, h_txt, W1t_img, W1t_txt, b1_img, b1_txt, g_img, g_txt,
      DH, DENC);
  // head 2 + normalize fused -> reps bf16 [8192x128]
  head2_norm<<<dim3(B_ROWS / 64, 1, 2), 256, 0, stream>>>(
      g_img, g_txt, W2t_img, W2t_txt, b2_img, b2_txt, reps);

  sim_rowsum_kernel<<<dim3(16, NTOT / 128), 256, 0, stream>>>(reps, S);
  rowloss_kernel<<<NTOT / 4, 256, 0, stream>>>(reps, S, L);
  reduce_kernel<<<1, 1024, 0, stream>>>(L, (float*)d_out);
}